// Round 1
// baseline (104.161 us; speedup 1.0000x reference)
//
#include <hip/hip_runtime.h>
#include <math.h>

// Problem: out[n,o] = exp(A)*cos(B)
//   A = sum_i log(R)*Wr - K*Wi ;  B = sum_i log(R)*Wi + K*Wr
//   R = (|x|+eps)*g + (1-g) = 1 + g*(|x|+eps-1),  K = pi*(x<0)*g,  g = clip(G,0,1)
// n=8192, i=o=128. 134M logs -> VALU/transcendental bound (~15us floor).

#define NROWS 8192
#define DIM   128
#define NB    8          // rows per thread; 8192/8 = 1024 blocks = 2 waves/SIMD
#define PI_F  3.14159265358979323846f

typedef float v2f __attribute__((ext_vector_type(2)));

static __device__ __forceinline__ v2f vfma2(v2f a, v2f b, v2f c) {
#if defined(__has_builtin) && __has_builtin(__builtin_elementwise_fma)
    return __builtin_elementwise_fma(a, b, c);
#else
    v2f r; r.x = fmaf(a.x, b.x, c.x); r.y = fmaf(a.y, b.y, c.y); return r;
#endif
}

// ---------------------------------------------------------------------------
// Prep: am1ps[n,i] = (|x|-1, pi*(x<0))  [wave-uniform data for main kernel]
//       w4[i,o]   = (clip(G), Wr, Wi, 0) packed for a single dwordx4 load
// ---------------------------------------------------------------------------
__global__ __launch_bounds__(256) void prep_kernel(
    const float* __restrict__ x, const float* __restrict__ Wr,
    const float* __restrict__ Wi, const float* __restrict__ G,
    float2* __restrict__ amps, float4* __restrict__ w4)
{
    int idx = blockIdx.x * 256 + threadIdx.x;
    int stride = gridDim.x * 256;
    for (int t = idx; t < NROWS * DIM; t += stride) {
        float xv = x[t];
        // 1e-36f - 1.0f == -1.0f in fp32; eps only matters below fp32 resolution
        float am1 = fabsf(xv) - 1.0f;
        float ps  = (xv < 0.0f) ? PI_F : 0.0f;
        amps[t] = make_float2(am1, ps);
    }
    for (int t = idx; t < DIM * DIM; t += stride) {
        float g = fminf(fmaxf(G[t], 0.0f), 1.0f);
        w4[t] = make_float4(g, Wr[t], Wi[t], 0.0f);
    }
}

// ---------------------------------------------------------------------------
// Main: one thread per output column o, NB rows per thread.
// x-derived loads are uniform (blockIdx/loop-index addressed) -> s_load.
// accL = (sum log2(t)*wr, sum log2(t)*wi); accK = (sum ps*g*wi, sum ps*g*wr)
// A = ln2*accL.x - accK.x ; B = ln2*accL.y + accK.y
// ---------------------------------------------------------------------------
__global__ __launch_bounds__(128) void main_kernel(
    const float2* __restrict__ amps, const float4* __restrict__ w4,
    float* __restrict__ out)
{
    const int o = threadIdx.x;
    const int nbase = blockIdx.x * NB;

    v2f accL[NB], accK[NB];
#pragma unroll
    for (int r = 0; r < NB; ++r) { accL[r] = (v2f){0.f, 0.f}; accK[r] = (v2f){0.f, 0.f}; }

    const float2* ap = amps + (size_t)nbase * DIM;

#pragma unroll 2
    for (int i = 0; i < DIM; ++i) {
        float4 w = w4[i * DIM + o];
        const float g = w.x, wr = w.y, wi = w.z;
        const v2f wv = {wr, wi};
        const v2f gv = {g * wi, g * wr};
#pragma unroll
        for (int r = 0; r < NB; ++r) {
            float2 a = ap[r * DIM + i];              // uniform -> s_load
            float t  = fmaf(a.x, g, 1.0f);           // R = 1 + g*(|x|-1)
            float l  = __log2f(t);                   // v_log_f32
            v2f lv = {l, l};
            v2f pv = {a.y, a.y};
            accL[r] = vfma2(lv, wv, accL[r]);
            accK[r] = vfma2(pv, gv, accK[r]);
        }
    }

    const float LN2 = 0.69314718055994530942f;
#pragma unroll
    for (int r = 0; r < NB; ++r) {
        float A = fmaf(LN2, accL[r].x, -accK[r].x);
        float B = fmaf(LN2, accL[r].y,  accK[r].y);
        out[(size_t)(nbase + r) * DIM + o] = expf(A) * cosf(B);
    }
}

// ---------------------------------------------------------------------------
// Fallback (workspace too small): same math, inputs read directly.
// ---------------------------------------------------------------------------
__global__ __launch_bounds__(128) void fallback_kernel(
    const float* __restrict__ x, const float* __restrict__ Wr,
    const float* __restrict__ Wi, const float* __restrict__ G,
    float* __restrict__ out)
{
    const int o = threadIdx.x;
    const int nbase = blockIdx.x * NB;

    v2f accL[NB], accK[NB];
#pragma unroll
    for (int r = 0; r < NB; ++r) { accL[r] = (v2f){0.f, 0.f}; accK[r] = (v2f){0.f, 0.f}; }

    for (int i = 0; i < DIM; ++i) {
        float g  = fminf(fmaxf(G[i * DIM + o], 0.0f), 1.0f);
        float wr = Wr[i * DIM + o];
        float wi = Wi[i * DIM + o];
        const v2f wv = {wr, wi};
        const v2f gv = {g * wi, g * wr};
#pragma unroll
        for (int r = 0; r < NB; ++r) {
            float xv  = x[(size_t)(nbase + r) * DIM + i];   // uniform
            float am1 = fabsf(xv) - 1.0f;
            float ps  = (xv < 0.0f) ? PI_F : 0.0f;
            float t   = fmaf(am1, g, 1.0f);
            float l   = __log2f(t);
            v2f lv = {l, l};
            v2f pv = {ps, ps};
            accL[r] = vfma2(lv, wv, accL[r]);
            accK[r] = vfma2(pv, gv, accK[r]);
        }
    }

    const float LN2 = 0.69314718055994530942f;
#pragma unroll
    for (int r = 0; r < NB; ++r) {
        float A = fmaf(LN2, accL[r].x, -accK[r].x);
        float B = fmaf(LN2, accL[r].y,  accK[r].y);
        out[(size_t)(nbase + r) * DIM + o] = expf(A) * cosf(B);
    }
}

extern "C" void kernel_launch(void* const* d_in, const int* in_sizes, int n_in,
                              void* d_out, int out_size, void* d_ws, size_t ws_size,
                              hipStream_t stream) {
    const float* x  = (const float*)d_in[0];
    const float* Wr = (const float*)d_in[1];
    const float* Wi = (const float*)d_in[2];
    const float* G  = (const float*)d_in[3];
    float* out = (float*)d_out;

    const size_t amps_bytes = (size_t)NROWS * DIM * sizeof(float2);   // 8 MB
    const size_t w4_bytes   = (size_t)DIM * DIM * sizeof(float4);     // 256 KB
    if (ws_size >= amps_bytes + w4_bytes) {
        float2* amps = (float2*)d_ws;
        float4* w4   = (float4*)((char*)d_ws + amps_bytes);
        prep_kernel<<<1024, 256, 0, stream>>>(x, Wr, Wi, G, amps, w4);
        main_kernel<<<NROWS / NB, 128, 0, stream>>>(amps, w4, out);
    } else {
        fallback_kernel<<<NROWS / NB, 128, 0, stream>>>(x, Wr, Wi, G, out);
    }
}

// Round 2
// 98.118 us; speedup vs baseline: 1.0616x; 1.0616x over previous
//
#include <hip/hip_runtime.h>
#include <math.h>

// out[n,o] = exp(A)*cos(B)
//   A = sum_i log(R)*Wr - K*Wi ;  B = sum_i log(R)*Wi + K*Wr
//   R = 1 + g*(|x|-1),  K = pi*(x<0)*g,  g = clip(G,0,1)
// n=8192, i=o=128. VALU/transcendental-bound; log floor ~7us, total ~14us.
//
// R2 geometry: 512-thread blocks (o=128 x q=4 row-quarters, RPT=2 rows/thread)
// -> 1024 blocks x 8 waves = 8192 waves = 100% wave-slot occupancy (R1 was 25%).
// x staged in 8KB LDS per block (fused, no 8MB workspace round-trip).

#define NROWS 8192
#define DIM   128
#define RPB   8          // rows per block
#define NT    512        // threads per block
#define RPT   2          // rows per thread (RPB / (NT/DIM))
#define PI_F  3.14159265358979323846f

typedef float v2f __attribute__((ext_vector_type(2)));

static __device__ __forceinline__ v2f vfma2(v2f a, v2f b, v2f c) {
#if defined(__has_builtin) && __has_builtin(__builtin_elementwise_fma)
    return __builtin_elementwise_fma(a, b, c);
#else
    v2f r; r.x = fmaf(a.x, b.x, c.x); r.y = fmaf(a.y, b.y, c.y); return r;
#endif
}

// Pack weights: w4[i*DIM+o] = (g, wr, wi, 0). 256KB, one-time, ~2us.
__global__ __launch_bounds__(256) void prep_w(
    const float* __restrict__ Wr, const float* __restrict__ Wi,
    const float* __restrict__ G, float4* __restrict__ w4)
{
    int t = blockIdx.x * 256 + threadIdx.x;
    if (t < DIM * DIM) {
        float g = fminf(fmaxf(G[t], 0.0f), 1.0f);
        w4[t] = make_float4(g, Wr[t], Wi[t], 0.0f);
    }
}

template <bool PACKED>
__global__ __launch_bounds__(NT, 8) void main_kernel(
    const float* __restrict__ x, const float4* __restrict__ w4,
    const float* __restrict__ Wr, const float* __restrict__ Wi,
    const float* __restrict__ G, float* __restrict__ out)
{
    __shared__ float2 amps[RPB * DIM];   // (|x|-1, pi*sign) per (row,i); 8KB
    const int tid   = threadIdx.x;
    const int o     = tid & (DIM - 1);
    const int q     = tid >> 7;           // row-quarter 0..3
    const int nbase = blockIdx.x * RPB;

    // Stage x tile: 1024 floats, 512 threads x float2, coalesced.
    {
        const float2* xr = (const float2*)(x + (size_t)nbase * DIM);
        float2 v = xr[tid];
        float4 s;
        s.x = fabsf(v.x) - 1.0f;  s.y = (v.x < 0.0f) ? PI_F : 0.0f;
        s.z = fabsf(v.y) - 1.0f;  s.w = (v.y < 0.0f) ? PI_F : 0.0f;
        ((float4*)amps)[tid] = s;
    }
    __syncthreads();

    const float2* ap = amps + q * (RPT * DIM);   // this thread's 2 rows
    v2f aL0 = {0.f,0.f}, aK0 = {0.f,0.f}, aL1 = {0.f,0.f}, aK1 = {0.f,0.f};

#pragma unroll 4
    for (int i = 0; i < DIM; ++i) {
        float g, wr, wi;
        if (PACKED) {
            float4 w = w4[i * DIM + o];
            g = w.x; wr = w.y; wi = w.z;
        } else {
            g  = fminf(fmaxf(G[i * DIM + o], 0.0f), 1.0f);
            wr = Wr[i * DIM + o]; wi = Wi[i * DIM + o];
        }
        const v2f wv = {wr, wi};
        const v2f gv = {g * wi, g * wr};
        float2 a0 = ap[i];            // wave-uniform LDS -> broadcast
        float2 a1 = ap[DIM + i];
        float t0 = fmaf(a0.x, g, 1.0f);
        float t1 = fmaf(a1.x, g, 1.0f);
        float l0 = __log2f(t0);
        float l1 = __log2f(t1);
        aL0 = vfma2((v2f){l0, l0},     wv, aL0);
        aK0 = vfma2((v2f){a0.y, a0.y}, gv, aK0);
        aL1 = vfma2((v2f){l1, l1},     wv, aL1);
        aK1 = vfma2((v2f){a1.y, a1.y}, gv, aK1);
    }

    const float LN2 = 0.69314718055994530942f;
    {
        float A = fmaf(LN2, aL0.x, -aK0.x);
        float B = fmaf(LN2, aL0.y,  aK0.y);
        out[(size_t)(nbase + q * RPT) * DIM + o] = expf(A) * cosf(B);
    }
    {
        float A = fmaf(LN2, aL1.x, -aK1.x);
        float B = fmaf(LN2, aL1.y,  aK1.y);
        out[(size_t)(nbase + q * RPT + 1) * DIM + o] = expf(A) * cosf(B);
    }
}

extern "C" void kernel_launch(void* const* d_in, const int* in_sizes, int n_in,
                              void* d_out, int out_size, void* d_ws, size_t ws_size,
                              hipStream_t stream) {
    const float* x  = (const float*)d_in[0];
    const float* Wr = (const float*)d_in[1];
    const float* Wi = (const float*)d_in[2];
    const float* G  = (const float*)d_in[3];
    float* out = (float*)d_out;

    const size_t w4_bytes = (size_t)DIM * DIM * sizeof(float4);   // 256 KB
    if (ws_size >= w4_bytes) {
        float4* w4 = (float4*)d_ws;
        prep_w<<<(DIM * DIM + 255) / 256, 256, 0, stream>>>(Wr, Wi, G, w4);
        main_kernel<true><<<NROWS / RPB, NT, 0, stream>>>(x, w4, Wr, Wi, G, out);
    } else {
        main_kernel<false><<<NROWS / RPB, NT, 0, stream>>>(x, nullptr, Wr, Wi, G, out);
    }
}

// Round 3
// 86.611 us; speedup vs baseline: 1.2026x; 1.1329x over previous
//
#include <hip/hip_runtime.h>
#include <math.h>

// out[n,o] = exp(A)*cos(B)
//   A = sum_i ln(R)*Wr - K*Wi ;  B = sum_i ln(R)*Wi + K*Wr
//   R = 1 + g*(|x|-1),  K = pi*(x<0)*g,  g = clip(G,0,1)
// n=8192, i=o=128. VALU/log-bound.
//
// R3: block = 512 thr = (o:128) x (q:4 i-quarters). Each thread: fixed o,
// 32 i's, 8 rows register-accumulated -> every (i,o) weight loaded ONCE per
// block (R2 loaded it 4x -> 1 GB L1/L2 re-read, 33% stall). Weights prepped
// as (ln2*wr, ln2*wi, -g*wi, g*wr)+g so inner body per 2 elems = 1 pk_fma(t)
// + 2 v_log + 4 pk_fma(acc). x staged as LDS SoA planes [i][r] -> broadcast
// ds_read_b128, rows pack into v_pk_fma_f32. i-quarter partials reduced via
// LDS overlay (planes dead after main loop; 32 KB total).

#define NROWS 8192
#define DIM   128
#define RPB   8           // rows per block (register-accumulated per thread)
#define NT    512
#define IQ    32          // i's per thread (DIM/4 quarters)
#define PI_F  3.14159265358979323846f
#define LN2_F 0.69314718055994530942f

typedef float v2f __attribute__((ext_vector_type(2)));

static __device__ __forceinline__ v2f vfma2(v2f a, v2f b, v2f c) {
    return __builtin_elementwise_fma(a, b, c);
}

// wq[i*DIM+o] = (ln2*wr, ln2*wi, -g*wi, g*wr); garr = g. One-time, ~64 blocks.
__global__ __launch_bounds__(256) void prep_w(
    const float* __restrict__ Wr, const float* __restrict__ Wi,
    const float* __restrict__ G, float4* __restrict__ wq,
    float* __restrict__ garr)
{
    int t = blockIdx.x * 256 + threadIdx.x;
    if (t < DIM * DIM) {
        float g  = fminf(fmaxf(G[t], 0.0f), 1.0f);
        float wr = Wr[t], wi = Wi[t];
        wq[t]   = make_float4(LN2_F * wr, LN2_F * wi, -g * wi, g * wr);
        garr[t] = g;
    }
}

template <bool PACKED>
__global__ __launch_bounds__(NT, 6) void main_kernel(
    const float* __restrict__ x, const float4* __restrict__ wq,
    const float* __restrict__ garr,
    const float* __restrict__ Wr, const float* __restrict__ Wi,
    const float* __restrict__ G, float* __restrict__ out)
{
    // 32 KB: first 2048 floats = am1/ps planes during main loop,
    // then overlaid by A/B partials (4096 floats each) for the reduce.
    __shared__ float sbuf[2 * 4 * RPB * DIM];
    float* am1p = sbuf;               // [DIM][RPB]
    float* psp  = sbuf + DIM * RPB;   // [DIM][RPB]

    const int tid   = threadIdx.x;
    const int o     = tid & (DIM - 1);
    const int q     = tid >> 7;            // i-quarter 0..3
    const int nbase = blockIdx.x * RPB;
    const float* xb = x + (size_t)nbase * DIM;

    // Stage x tile as SoA planes (coalesced global reads; one-time scatter).
#pragma unroll
    for (int k = 0; k < 2; ++k) {
        int e = tid + k * NT;
        float xv = xb[e];
        int i = e & (DIM - 1), r = e >> 7;
        am1p[i * RPB + r] = fabsf(xv) - 1.0f;
        psp[i * RPB + r]  = (xv < 0.0f) ? PI_F : 0.0f;
    }
    __syncthreads();

    v2f accA[4], accB[4];
#pragma unroll
    for (int p = 0; p < 4; ++p) { accA[p] = (v2f){0.f, 0.f}; accB[p] = (v2f){0.f, 0.f}; }

    const int ibase = q * IQ;
#pragma unroll 2
    for (int ii = 0; ii < IQ; ++ii) {
        const int i = ibase + ii;
        float wrl, wil, ngwi, gwr, g;
        if (PACKED) {
            float4 w = wq[i * DIM + o];
            g = garr[i * DIM + o];
            wrl = w.x; wil = w.y; ngwi = w.z; gwr = w.w;
        } else {
            float wr = Wr[i * DIM + o], wi = Wi[i * DIM + o];
            g = fminf(fmaxf(G[i * DIM + o], 0.0f), 1.0f);
            wrl = LN2_F * wr; wil = LN2_F * wi; ngwi = -g * wi; gwr = g * wr;
        }
        const v2f gg2   = {g, g};
        const v2f wrl2  = {wrl, wrl};
        const v2f wil2  = {wil, wil};
        const v2f ngwi2 = {ngwi, ngwi};
        const v2f gwr2  = {gwr, gwr};
        const v2f one2  = {1.0f, 1.0f};

        // 8 rows via 2+2 broadcast ds_read_b128 (16B-aligned: 32*i bytes)
        const float4* a4 = (const float4*)(am1p + i * RPB);
        const float4* p4 = (const float4*)(psp  + i * RPB);
        float4 a03 = a4[0], a47 = a4[1];
        float4 s03 = p4[0], s47 = p4[1];

#define ROWPAIR(mx, my, sx, sy, idx)                                        \
        do {                                                                \
            v2f t2 = vfma2((v2f){mx, my}, gg2, one2);                       \
            v2f l2 = { __log2f(t2.x), __log2f(t2.y) };                      \
            v2f s2 = {sx, sy};                                              \
            accA[idx] = vfma2(l2, wrl2, vfma2(s2, ngwi2, accA[idx]));       \
            accB[idx] = vfma2(l2, wil2, vfma2(s2, gwr2,  accB[idx]));       \
        } while (0)

        ROWPAIR(a03.x, a03.y, s03.x, s03.y, 0);
        ROWPAIR(a03.z, a03.w, s03.z, s03.w, 1);
        ROWPAIR(a47.x, a47.y, s47.x, s47.y, 2);
        ROWPAIR(a47.z, a47.w, s47.z, s47.w, 3);
#undef ROWPAIR
    }

    // Reduce partials across the 4 i-quarters (planes are dead now).
    __syncthreads();
    float* pA = sbuf;                    // [4][RPB][DIM]
    float* pB = sbuf + 4 * RPB * DIM;    // [4][RPB][DIM]
#pragma unroll
    for (int p = 0; p < 4; ++p) {
        pA[q * (RPB * DIM) + (2 * p) * DIM + o]     = accA[p].x;
        pA[q * (RPB * DIM) + (2 * p + 1) * DIM + o] = accA[p].y;
        pB[q * (RPB * DIM) + (2 * p) * DIM + o]     = accB[p].x;
        pB[q * (RPB * DIM) + (2 * p + 1) * DIM + o] = accB[p].y;
    }
    __syncthreads();

    const int e  = tid * 2;
    const int r  = e >> 7, oo = e & (DIM - 1);
    v2f A = {0.f, 0.f}, B = {0.f, 0.f};
#pragma unroll
    for (int qq = 0; qq < 4; ++qq) {
        A += *(const v2f*)&pA[qq * (RPB * DIM) + r * DIM + oo];
        B += *(const v2f*)&pB[qq * (RPB * DIM) + r * DIM + oo];
    }
    float2 res;
    res.x = __expf(A.x) * __cosf(B.x);
    res.y = __expf(A.y) * __cosf(B.y);
    *(float2*)&out[(size_t)(nbase + r) * DIM + oo] = res;
}

extern "C" void kernel_launch(void* const* d_in, const int* in_sizes, int n_in,
                              void* d_out, int out_size, void* d_ws, size_t ws_size,
                              hipStream_t stream) {
    const float* x  = (const float*)d_in[0];
    const float* Wr = (const float*)d_in[1];
    const float* Wi = (const float*)d_in[2];
    const float* G  = (const float*)d_in[3];
    float* out = (float*)d_out;

    const size_t wq_bytes = (size_t)DIM * DIM * sizeof(float4);   // 256 KB
    const size_t g_bytes  = (size_t)DIM * DIM * sizeof(float);    // 64 KB
    if (ws_size >= wq_bytes + g_bytes) {
        float4* wq   = (float4*)d_ws;
        float*  garr = (float*)((char*)d_ws + wq_bytes);
        prep_w<<<(DIM * DIM + 255) / 256, 256, 0, stream>>>(Wr, Wi, G, wq, garr);
        main_kernel<true><<<NROWS / RPB, NT, 0, stream>>>(x, wq, garr,
                                                          nullptr, nullptr, nullptr, out);
    } else {
        main_kernel<false><<<NROWS / RPB, NT, 0, stream>>>(x, nullptr, nullptr,
                                                           Wr, Wi, G, out);
    }
}

// Round 4
// 85.744 us; speedup vs baseline: 1.2148x; 1.0101x over previous
//
#include <hip/hip_runtime.h>
#include <math.h>

// out[n,o] = exp(A)*cos(B)
//   A = sum_i ln(R)*Wr - K*Wi ;  B = sum_i ln(R)*Wi + K*Wr
//   R = 1 + g*(|x|-1),  K = pi*(x<0)*g,  g = clip(G,0,1)
// n=8192, i=o=128. VALU/log-bound; floor ~12us (134M v_log @ 1/4 rate + pk-FMAs).
//
// R4: RPB 8->16. Block = 512 thr = (o:128)x(q:4 i-quarters); each thread:
// fixed o, 32 i's, 16 rows register-accumulated (accA/accB[8] v2f pairs).
// Per-iter VALU ~208cy vs 2 weight loads -> weight traffic/elem halved vs R3,
// latency hiding doubled. 512 blocks x 8 waves = 4096 waves = 2 blocks/CU
// (64KB LDS each, 128<=160KB), 4 waves/SIMD. Epilogue: A/B partial buffers
// overlay dead x-planes (32+32KB), 2 syncs, float4 coalesced store.

#define NROWS 8192
#define DIM   128
#define RPB   16          // rows per block (register-accumulated per thread)
#define NT    512
#define IQ    32          // i's per thread (DIM/4 quarters)
#define PI_F  3.14159265358979323846f
#define LN2_F 0.69314718055994530942f

typedef float v2f __attribute__((ext_vector_type(2)));
typedef float v4f __attribute__((ext_vector_type(4)));

static __device__ __forceinline__ v2f vfma2(v2f a, v2f b, v2f c) {
    return __builtin_elementwise_fma(a, b, c);
}

// wq[i*DIM+o] = (ln2*wr, ln2*wi, -g*wi, g*wr); garr = g. One-time, 64 blocks.
__global__ __launch_bounds__(256) void prep_w(
    const float* __restrict__ Wr, const float* __restrict__ Wi,
    const float* __restrict__ G, float4* __restrict__ wq,
    float* __restrict__ garr)
{
    int t = blockIdx.x * 256 + threadIdx.x;
    if (t < DIM * DIM) {
        float g  = fminf(fmaxf(G[t], 0.0f), 1.0f);
        float wr = Wr[t], wi = Wi[t];
        wq[t]   = make_float4(LN2_F * wr, LN2_F * wi, -g * wi, g * wr);
        garr[t] = g;
    }
}

template <bool PACKED>
__global__ __launch_bounds__(NT, 4) void main_kernel(
    const float* __restrict__ x, const float4* __restrict__ wq,
    const float* __restrict__ garr,
    const float* __restrict__ Wr, const float* __restrict__ Wi,
    const float* __restrict__ G, float* __restrict__ out)
{
    // 64 KB. During main loop: am1/ps planes [DIM][RPB] in first 4096 floats.
    // Epilogue: pA = sbuf[0..8191], pB = sbuf[8192..16383], each [4][RPB][DIM].
    __shared__ float sbuf[2 * 4 * RPB * DIM];
    float* am1p = sbuf;               // [DIM][RPB]
    float* psp  = sbuf + DIM * RPB;   // [DIM][RPB]

    const int tid   = threadIdx.x;
    const int o     = tid & (DIM - 1);
    const int q     = tid >> 7;            // i-quarter 0..3
    const int nbase = blockIdx.x * RPB;
    const float* xb = x + (size_t)nbase * DIM;

    // Stage x tile (2048 floats) as SoA planes. float4 coalesced reads;
    // stride-RPB LDS scatter has conflicts but is one-time per block.
    {
        float4 v = ((const float4*)xb)[tid];
        int e = tid * 4;
        int r = e >> 7;            // row 0..15
        int i = e & (DIM - 1);     // first of 4 consecutive i
        am1p[(i + 0) * RPB + r] = fabsf(v.x) - 1.0f;
        am1p[(i + 1) * RPB + r] = fabsf(v.y) - 1.0f;
        am1p[(i + 2) * RPB + r] = fabsf(v.z) - 1.0f;
        am1p[(i + 3) * RPB + r] = fabsf(v.w) - 1.0f;
        psp[(i + 0) * RPB + r]  = (v.x < 0.0f) ? PI_F : 0.0f;
        psp[(i + 1) * RPB + r]  = (v.y < 0.0f) ? PI_F : 0.0f;
        psp[(i + 2) * RPB + r]  = (v.z < 0.0f) ? PI_F : 0.0f;
        psp[(i + 3) * RPB + r]  = (v.w < 0.0f) ? PI_F : 0.0f;
    }
    __syncthreads();

    v2f accA[8], accB[8];
#pragma unroll
    for (int p = 0; p < 8; ++p) { accA[p] = (v2f){0.f, 0.f}; accB[p] = (v2f){0.f, 0.f}; }

    const int ibase = q * IQ;
#pragma unroll 2
    for (int ii = 0; ii < IQ; ++ii) {
        const int i = ibase + ii;
        float wrl, wil, ngwi, gwr, g;
        if (PACKED) {
            float4 w = wq[i * DIM + o];
            g = garr[i * DIM + o];
            wrl = w.x; wil = w.y; ngwi = w.z; gwr = w.w;
        } else {
            float wr = Wr[i * DIM + o], wi = Wi[i * DIM + o];
            g = fminf(fmaxf(G[i * DIM + o], 0.0f), 1.0f);
            wrl = LN2_F * wr; wil = LN2_F * wi; ngwi = -g * wi; gwr = g * wr;
        }
        const v2f gg2   = {g, g};
        const v2f wrl2  = {wrl, wrl};
        const v2f wil2  = {wil, wil};
        const v2f ngwi2 = {ngwi, ngwi};
        const v2f gwr2  = {gwr, gwr};
        const v2f one2  = {1.0f, 1.0f};

        // 16 rows via 4+4 broadcast ds_read_b128 (all lanes same addr).
        const float4* a4 = (const float4*)(am1p + i * RPB);
        const float4* p4 = (const float4*)(psp  + i * RPB);

#define ROWPAIR(mx, my, sx, sy, idx)                                        \
        do {                                                                \
            v2f t2 = vfma2((v2f){mx, my}, gg2, one2);                       \
            v2f l2 = { __log2f(t2.x), __log2f(t2.y) };                      \
            v2f s2 = {sx, sy};                                              \
            accA[idx] = vfma2(l2, wrl2, vfma2(s2, ngwi2, accA[idx]));       \
            accB[idx] = vfma2(l2, wil2, vfma2(s2, gwr2,  accB[idx]));       \
        } while (0)

#pragma unroll
        for (int p = 0; p < 4; ++p) {
            float4 a = a4[p], s = p4[p];
            ROWPAIR(a.x, a.y, s.x, s.y, 2 * p);
            ROWPAIR(a.z, a.w, s.z, s.w, 2 * p + 1);
        }
#undef ROWPAIR
    }

    // Reduce partials across the 4 i-quarters (planes dead now).
    __syncthreads();
    float* pA = sbuf;                    // [4][RPB][DIM]
    float* pB = sbuf + 4 * RPB * DIM;    // [4][RPB][DIM]
#pragma unroll
    for (int p = 0; p < 8; ++p) {
        pA[q * (RPB * DIM) + (2 * p) * DIM + o]     = accA[p].x;
        pA[q * (RPB * DIM) + (2 * p + 1) * DIM + o] = accA[p].y;
        pB[q * (RPB * DIM) + (2 * p) * DIM + o]     = accB[p].x;
        pB[q * (RPB * DIM) + (2 * p + 1) * DIM + o] = accB[p].y;
    }
    __syncthreads();

    // Each thread finishes 4 consecutive (r,o) cells; float4 coalesced store.
    const int c  = tid * 4;
    const int r  = c >> 7, oo = c & (DIM - 1);
    v4f A = {0.f, 0.f, 0.f, 0.f}, B = {0.f, 0.f, 0.f, 0.f};
#pragma unroll
    for (int qq = 0; qq < 4; ++qq) {
        A += *(const v4f*)&pA[qq * (RPB * DIM) + r * DIM + oo];
        B += *(const v4f*)&pB[qq * (RPB * DIM) + r * DIM + oo];
    }
    float4 res;
    res.x = __expf(A.x) * __cosf(B.x);
    res.y = __expf(A.y) * __cosf(B.y);
    res.z = __expf(A.z) * __cosf(B.z);
    res.w = __expf(A.w) * __cosf(B.w);
    *(float4*)&out[(size_t)(nbase + r) * DIM + oo] = res;
}

extern "C" void kernel_launch(void* const* d_in, const int* in_sizes, int n_in,
                              void* d_out, int out_size, void* d_ws, size_t ws_size,
                              hipStream_t stream) {
    const float* x  = (const float*)d_in[0];
    const float* Wr = (const float*)d_in[1];
    const float* Wi = (const float*)d_in[2];
    const float* G  = (const float*)d_in[3];
    float* out = (float*)d_out;

    const size_t wq_bytes = (size_t)DIM * DIM * sizeof(float4);   // 256 KB
    const size_t g_bytes  = (size_t)DIM * DIM * sizeof(float);    // 64 KB
    if (ws_size >= wq_bytes + g_bytes) {
        float4* wq   = (float4*)d_ws;
        float*  garr = (float*)((char*)d_ws + wq_bytes);
        prep_w<<<(DIM * DIM + 255) / 256, 256, 0, stream>>>(Wr, Wi, G, wq, garr);
        main_kernel<true><<<NROWS / RPB, NT, 0, stream>>>(x, wq, garr,
                                                          nullptr, nullptr, nullptr, out);
    } else {
        main_kernel<false><<<NROWS / RPB, NT, 0, stream>>>(x, nullptr, nullptr,
                                                           Wr, Wi, G, out);
    }
}